// Round 14
// baseline (385.972 us; speedup 1.0000x reference)
//
#include <hip/hip_runtime.h>
#include <hip/hip_bf16.h>
#include <math.h>

// WaveletLayer: DWT(db2) -> conv3+GELU (x2) -> IDWT -> out-projection.
// Round 14 (= Round 13 resubmit; bench infra timed out): 6 dispatches -> 3.
//   1) fused_prep = dwt + conv-weight prep + wout prep (block-partitioned).
//   2) conv_mm unchanged (T3-min pipeline, verified).
//   3) fused_out = idwt folded into out-GEMM: A-tile reg-staged from pout
//      (T14 issue-early/write-late), rc buffer eliminated (-67 MB traffic).

namespace {

constexpr int Hc = 1024;
constexpr int Sc = 2048;
constexpr int Mcv = 1024;   // conv seq len (S/2)
constexpr int AROWS = 1026; // conv A rows per batch-plane (1 guard each side)

constexpr double S3d = 1.7320508075688772935274463;
constexpr double DNd = 5.6568542494923801952067549;  // 4*sqrt(2)
constexpr float W0 = (float)((1.0 + S3d) / DNd);
constexpr float W1 = (float)((3.0 + S3d) / DNd);
constexpr float W2 = (float)((3.0 - S3d) / DNd);
constexpr float W3 = (float)((1.0 - S3d) / DNd);

typedef short bf16x8 __attribute__((ext_vector_type(8)));
typedef unsigned short u16x8 __attribute__((ext_vector_type(8)));
typedef float f32x4 __attribute__((ext_vector_type(4)));

typedef __attribute__((address_space(1))) const unsigned char ga_u8;
typedef __attribute__((address_space(3))) unsigned char la_u8;

__device__ __forceinline__ void gload16(const void* g, void* l) {
  __builtin_amdgcn_global_load_lds((ga_u8*)g, (la_u8*)l, 16, 0, 0);
}

__device__ __forceinline__ unsigned short rnd1(float v) {
  __hip_bfloat16 hb = __float2bfloat16(v);
  return *reinterpret_cast<unsigned short*>(&hb);
}

__device__ __forceinline__ float b2f(unsigned short s) {
  union { unsigned int u; float f; } c;
  c.u = ((unsigned int)s) << 16;
  return c.f;
}

__device__ __forceinline__ ushort4 rnd4(const float4 v) {
  ushort4 h;
  h.x = rnd1(v.x); h.y = rnd1(v.y); h.z = rnd1(v.z); h.w = rnd1(v.w);
  return h;
}

__device__ __forceinline__ void split1(float v, unsigned short& h, unsigned short& l) {
  __hip_bfloat16 hb = __float2bfloat16(v);
  float r = v - __bfloat162float(hb);
  __hip_bfloat16 lb = __float2bfloat16(r);
  h = *reinterpret_cast<unsigned short*>(&hb);
  l = *reinterpret_cast<unsigned short*>(&lb);
}

__device__ __forceinline__ void split4(const float4 v, ushort4& h, ushort4& l) {
  split1(v.x, h.x, l.x);
  split1(v.y, h.y, l.y);
  split1(v.z, h.z, l.z);
  split1(v.w, h.w, l.w);
}

// ---------------------------------------------------------------- fused prep
// Blocks [0,4096): DWT (paired, merged A plane: batches 0..7 = ca, 8..15 = cd)
// Blocks [4096,6144): conv weight prep (w[o][i][k] -> per-tap [k][o][i] hi/lo)
// Blocks [6144,7168): wout prep (hi/lo split)
__global__ void fused_prep_kernel(
    const float* __restrict__ x, unsigned short* __restrict__ A,
    const float* __restrict__ wA, const float* __restrict__ wD,
    unsigned short* __restrict__ aH, unsigned short* __restrict__ aL,
    unsigned short* __restrict__ dH, unsigned short* __restrict__ dL,
    const float* __restrict__ wo,
    unsigned short* __restrict__ oh, unsigned short* __restrict__ ol) {
  const int bid = blockIdx.x;
  if (bid < 4096) {
    // ---- DWT: paired, each thread computes m and m+1
    const int tid = bid * 256 + threadIdx.x;  // 2^20 threads
    const int h4 = (tid & 255) << 2;
    const int mp = (tid >> 8) & 511;
    const int b = tid >> 17;
    const int m = mp * 2;
    const float* xb = x + (size_t)b * Sc * Hc;
    float4 v[6];
#pragma unroll
    for (int t = 0; t < 6; ++t) {
      int i = 2 * m - 2 + t;
      if (i < 0) i = -i - 1;  // symmetric left reflection
      v[t] = *reinterpret_cast<const float4*>(&xb[(size_t)i * Hc + h4]);
    }
    float4 a0, d0, a1, d1;
#define DWT_AD(ao, dd, u0, u1, u2, u3)                      \
    ao.x = W0*u0.x + W1*u1.x + W2*u2.x + W3*u3.x;           \
    ao.y = W0*u0.y + W1*u1.y + W2*u2.y + W3*u3.y;           \
    ao.z = W0*u0.z + W1*u1.z + W2*u2.z + W3*u3.z;           \
    ao.w = W0*u0.w + W1*u1.w + W2*u2.w + W3*u3.w;           \
    dd.x = W3*u0.x - W2*u1.x + W1*u2.x - W0*u3.x;           \
    dd.y = W3*u0.y - W2*u1.y + W1*u2.y - W0*u3.y;           \
    dd.z = W3*u0.z - W2*u1.z + W1*u2.z - W0*u3.z;           \
    dd.w = W3*u0.w - W2*u1.w + W1*u2.w - W0*u3.w;
    DWT_AD(a0, d0, v[0], v[1], v[2], v[3]);
    DWT_AD(a1, d1, v[2], v[3], v[4], v[5]);
#undef DWT_AD
    const size_t rowA = (size_t)b * AROWS + 1 + m;
    const size_t rowD = (size_t)(b + 8) * AROWS + 1 + m;
    *reinterpret_cast<ushort4*>(&A[rowA * Hc + h4]) = rnd4(a0);
    *reinterpret_cast<ushort4*>(&A[(rowA + 1) * Hc + h4]) = rnd4(a1);
    *reinterpret_cast<ushort4*>(&A[rowD * Hc + h4]) = rnd4(d0);
    *reinterpret_cast<ushort4*>(&A[(rowD + 1) * Hc + h4]) = rnd4(d1);
    if (mp == 0) {  // zero the 4 guard rows this (b,h4) owns
      const ushort4 z4 = {0, 0, 0, 0};
      const size_t gr[4] = {(size_t)b * AROWS,       (size_t)b * AROWS + AROWS - 1,
                            (size_t)(b + 8) * AROWS, (size_t)(b + 8) * AROWS + AROWS - 1};
#pragma unroll
      for (int i = 0; i < 4; ++i)
        *reinterpret_cast<ushort4*>(&A[gr[i] * Hc + h4]) = z4;
    }
  } else if (bid < 6144) {
    // ---- conv weight prep
    const int idx = (bid - 4096) * 256 + threadIdx.x;  // 2*1024*256
    const int i4 = idx & 255;
    const int o = (idx >> 8) & 1023;
    const int c = idx >> 18;
    const float* w = c ? wD : wA;
    unsigned short* ohp = c ? dH : aH;
    unsigned short* olp = c ? dL : aL;
    const float* src = w + (size_t)o * 3072 + i4 * 12;
    const float4 f0 = *reinterpret_cast<const float4*>(src);
    const float4 f1 = *reinterpret_cast<const float4*>(src + 4);
    const float4 f2 = *reinterpret_cast<const float4*>(src + 8);
    const float e[12] = {f0.x, f0.y, f0.z, f0.w, f1.x, f1.y, f1.z, f1.w,
                         f2.x, f2.y, f2.z, f2.w};
#pragma unroll
    for (int k = 0; k < 3; ++k) {
      float4 v = make_float4(e[k], e[3 + k], e[6 + k], e[9 + k]);
      ushort4 hh, ll;
      split4(v, hh, ll);
      const size_t off = (size_t)k * 1048576 + (size_t)o * 1024 + i4 * 4;
      *reinterpret_cast<ushort4*>(&ohp[off]) = hh;
      *reinterpret_cast<ushort4*>(&olp[off]) = ll;
    }
  } else {
    // ---- wout prep
    const int idx = (bid - 6144) * 256 + threadIdx.x;  // 1024*256
    const size_t off = (size_t)(idx >> 8) * 1024 + (idx & 255) * 4;
    ushort4 hh, ll;
    split4(*reinterpret_cast<const float4*>(&wo[off]), hh, ll);
    *reinterpret_cast<ushort4*>(&oh[off]) = hh;
    *reinterpret_cast<ushort4*>(&ol[off]) = ll;
  }
}

// ---------------------------------------------------------------- conv MFMA
// BM=256 x BN=128, 512 threads (8 waves, 2 wm x 4 wn; wave = 128 rows x 32
// cols, acc 8x2). Tap-shared A (258 rows). T3-min pipeline: LDS double
// buffer; per k-step STAGE(next) -> compute(cur) -> one __syncthreads.
// Grid 512: t = id&3, o = (id>>2)&7, z = id>>5. Output pout is bf16.
__global__ __launch_bounds__(512, 2) void conv_mm_kernel(
    const unsigned short* __restrict__ A,
    const unsigned short* __restrict__ BAh, const unsigned short* __restrict__ BAl,
    const unsigned short* __restrict__ BDh, const unsigned short* __restrict__ BDl,
    const float* __restrict__ biasA, const float* __restrict__ biasD,
    unsigned short* __restrict__ Yout) {
  // per buffer (ushorts): As[258][32] @0 (8256), Bs[tp][128][32] @8256+tp*4096
  __shared__ __align__(16) unsigned short lds[65664];

  const int tid = threadIdx.x;
  const int lane = tid & 63;
  const int wave = tid >> 6;           // 0..7
  const int wm = wave >> 2;            // 0..1
  const int wn = wave & 3;             // 0..3

  const int id = blockIdx.x;
  const int t = id & 3;
  const int o = (id >> 2) & 7;
  const int z = id >> 5;               // 0..15
  const int o0 = o * 128;
  const int t0 = t * 256;
  const int arow0 = z * AROWS + t0;

  const unsigned short* BH = (z < 8) ? BAh : BDh;
  const unsigned short* BL = (z < 8) ? BAl : BDl;
  const float* bias = (z < 8) ? biasA : biasD;

  f32x4 acc[8][2];
#pragma unroll
  for (int m = 0; m < 8; ++m)
#pragma unroll
    for (int n = 0; n < 2; ++n) acc[m][n] = (f32x4){0.f, 0.f, 0.f, 0.f};

  const int q = lane >> 2;
  const int srcslot = (lane & 3) ^ ((lane >> 3) & 3);  // pre-swizzled source slot
  const int l15 = lane & 15;
  const int g = lane >> 4;

#define CONV_STAGE(buf, c0)                                                     \
  {                                                                             \
    unsigned short* L = lds + (buf) * 32832;                                    \
    _Pragma("unroll")                                                           \
    for (int j = 0; j < 2; ++j) {                                               \
      const int seg = wave * 2 + j;                                             \
      const int r = seg * 16 + q;                                               \
      gload16(A + (size_t)(arow0 + r) * 1024 + (c0) + srcslot * 8,              \
              L + seg * 512);                                                   \
    }                                                                           \
    if (wave == 0 && lane < 8) {                                                \
      const int r = 256 + (lane >> 2);                                          \
      gload16(A + (size_t)(arow0 + r) * 1024 + (c0) + (lane & 3) * 8,           \
              L + 8192);                                                        \
    }                                                                           \
    _Pragma("unroll")                                                           \
    for (int j = 0; j < 6; ++j) {                                               \
      const int g6 = wave * 6 + j;                                              \
      const int tp = g6 >> 3;                                                   \
      const int seg = g6 & 7;                                                   \
      const unsigned short* bp =                                                \
          ((tp & 1) ? BL : BH) + (size_t)(tp >> 1) * 1048576;                   \
      const int r = seg * 16 + q;                                               \
      gload16(bp + (size_t)(o0 + r) * 1024 + (c0) + srcslot * 8,                \
              L + 8256 + tp * 4096 + seg * 512);                                \
    }                                                                           \
  }

  CONV_STAGE(0, 0);
  __syncthreads();

  int cur = 0;
#pragma unroll 1
  for (int step = 0; step < 32; ++step) {
    if (step < 31) CONV_STAGE(cur ^ 1, (step + 1) * 32);

    unsigned short* L = lds + cur * 32832;
#pragma unroll
    for (int tap = 0; tap < 3; ++tap) {
      bf16x8 a4[8];
#pragma unroll
      for (int m = 0; m < 8; ++m) {
        const int r = wm * 128 + m * 16 + l15 + tap;
        a4[m] = *reinterpret_cast<const bf16x8*>(L + r * 32 + (g ^ ((r >> 1) & 3)) * 8);
      }
#pragma unroll
      for (int n = 0; n < 2; ++n) {
        const int r = wn * 32 + n * 16 + l15;
        const int off = r * 32 + (g ^ ((r >> 1) & 3)) * 8;
        const bf16x8 bH4 = *reinterpret_cast<const bf16x8*>(L + 8256 + (tap * 2) * 4096 + off);
        const bf16x8 bL4 = *reinterpret_cast<const bf16x8*>(L + 8256 + (tap * 2 + 1) * 4096 + off);
#pragma unroll
        for (int m = 0; m < 8; ++m) {
          acc[m][n] = __builtin_amdgcn_mfma_f32_16x16x32_bf16(a4[m], bH4, acc[m][n], 0, 0, 0);
          acc[m][n] = __builtin_amdgcn_mfma_f32_16x16x32_bf16(a4[m], bL4, acc[m][n], 0, 0, 0);
        }
      }
    }
    __syncthreads();  // drains staged loads (covered by compute) + read-done
    cur ^= 1;
  }
#undef CONV_STAGE

  // epilogue: C/D frag col = lane&15, row = (lane>>4)*4 + reg  [m89]
  const int yrow0 = z * Mcv + t0 + wm * 128;
  constexpr float RS2 = 0.70710678118654752440f;
#pragma unroll
  for (int n = 0; n < 2; ++n) {
    const int col = o0 + wn * 32 + n * 16 + l15;
    const float bv = bias[col];
#pragma unroll
    for (int m = 0; m < 8; ++m) {
      const int rbase = yrow0 + m * 16 + g * 4;
#pragma unroll
      for (int r = 0; r < 4; ++r) {
        float v = acc[m][n][r] + bv;
        v = 0.5f * v * (1.f + erff(v * RS2));
        Yout[(size_t)(rbase + r) * 1024 + col] = rnd1(v);
      }
    }
  }
}

// ---------------------------------------------------------------- fused out
// IDWT folded into the out-GEMM. BM=256 x BN=256, 512 threads (8 waves 2x4,
// acc 8x4/wave). A-tile is reg-staged from pout (T14: issue loads early,
// idwt-compute + swizzled ds_write after the MFMA block); B via gload_lds.
// Grid 256, XCD-chunked: wgid = (id&7)*32 + id>>3; rowt = wgid>>2 (0..63),
// colt = wgid&3. Row panel rowt -> batch b = rowt>>3, j0 = (rowt&7)*128.
// A row lr=2*jj   (s=2j):   W0*pa[j+1] + W2*pa[j] + W3*pd[j+1] + W1*pd[j]
// A row lr=2*jj+1 (s=2j+1): W1*pa[j+1] + W3*pa[j] - W2*pd[j+1] - W0*pd[j]
// j == 1023 -> rows 2046,2047 are zero padding.
__global__ __launch_bounds__(512, 2) void fused_out_kernel(
    const unsigned short* __restrict__ pout,
    const unsigned short* __restrict__ Bhi, const unsigned short* __restrict__ Blo,
    const float* __restrict__ bias, float* __restrict__ out) {
  // per buffer (ushorts): As[256][32] @0 (8192), BsH[256][32] @8192, BsL @16384
  __shared__ __align__(16) unsigned short lds[49152];

  const int tid = threadIdx.x;
  const int lane = tid & 63;
  const int wave = tid >> 6;          // 0..7
  const int wm = wave >> 2;           // 0..1
  const int wn = wave & 3;            // 0..3

  const int id = blockIdx.x;                     // 0..255
  const int wgid = (id & 7) * 32 + (id >> 3);    // bijective XCD chunking
  const int rowt = wgid >> 2;                    // 0..63
  const int colt = wgid & 3;                     // 0..3
  const int o0 = colt * 256;
  const int t0 = rowt * 256;
  const int b = rowt >> 3;
  const int j0 = (rowt & 7) * 128;

  const unsigned short* pab = pout + (size_t)b * Mcv * Hc;
  const unsigned short* pdb = pout + (size_t)(b + 8) * Mcv * Hc;

  // A reg-staging geometry: thread -> (jj, oct); covers 128 j x 4 col-octets
  const int jj = tid >> 2;            // 0..127
  const int oct = tid & 3;            // 0..3
  const int aj = j0 + jj;             // pout row j
  const int lr0 = jj * 2;             // local A rows lr0, lr0+1
  const int aslot = oct ^ (jj & 3);   // swizzle key (lr>>1)&3 == jj&3
  u16x8 vaL, vaH, vdL, vdH;

#define FO_LOADA(c0)                                                          \
  if (aj < 1023) {                                                            \
    const size_t pb = (size_t)aj * 1024 + (c0) + oct * 8;                     \
    vaL = *reinterpret_cast<const u16x8*>(pab + pb);                          \
    vaH = *reinterpret_cast<const u16x8*>(pab + pb + 1024);                   \
    vdL = *reinterpret_cast<const u16x8*>(pdb + pb);                          \
    vdH = *reinterpret_cast<const u16x8*>(pdb + pb + 1024);                   \
  }

#define FO_WRITEA(buf)                                                        \
  {                                                                           \
    u16x8 r0, r1;                                                             \
    if (aj < 1023) {                                                          \
      _Pragma("unroll")                                                       \
      for (int e = 0; e < 8; ++e) {                                           \
        const float faL = b2f(vaL[e]), faH = b2f(vaH[e]);                     \
        const float fdL = b2f(vdL[e]), fdH = b2f(vdH[e]);                     \
        r0[e] = rnd1(W0 * faH + W2 * faL + W3 * fdH + W1 * fdL);              \
        r1[e] = rnd1(W1 * faH + W3 * faL - W2 * fdH - W0 * fdL);              \
      }                                                                       \
    } else {                                                                  \
      r0 = (u16x8){0, 0, 0, 0, 0, 0, 0, 0};                                   \
      r1 = (u16x8){0, 0, 0, 0, 0, 0, 0, 0};                                   \
    }                                                                         \
    unsigned short* Lw = lds + (buf) * 24576;                                 \
    *reinterpret_cast<u16x8*>(Lw + lr0 * 32 + aslot * 8) = r0;                \
    *reinterpret_cast<u16x8*>(Lw + (lr0 + 1) * 32 + aslot * 8) = r1;          \
  }

  const int q = lane >> 2;
  const int srcslot = (lane & 3) ^ ((lane >> 3) & 3);
  const int l15 = lane & 15;
  const int g = lane >> 4;

#define FO_STAGE_B(buf, c0)                                                   \
  {                                                                           \
    unsigned short* L = lds + (buf) * 24576;                                  \
    _Pragma("unroll")                                                         \
    for (int jb = 0; jb < 4; ++jb) {                                          \
      const int g4 = wave * 4 + jb;                                           \
      const int pl = g4 >> 4;                                                 \
      const int seg = g4 & 15;                                                \
      const unsigned short* bp = pl ? Blo : Bhi;                              \
      const int r = seg * 16 + q;                                             \
      gload16(bp + (size_t)(o0 + r) * 1024 + (c0) + srcslot * 8,              \
              L + 8192 + pl * 8192 + seg * 512);                              \
    }                                                                         \
  }

  f32x4 acc[8][4];
#pragma unroll
  for (int m = 0; m < 8; ++m)
#pragma unroll
    for (int n = 0; n < 4; ++n) acc[m][n] = (f32x4){0.f, 0.f, 0.f, 0.f};

  // prologue: stage k-step 0 into buf 0
  FO_LOADA(0);
  FO_STAGE_B(0, 0);
  FO_WRITEA(0);
  __syncthreads();

  int cur = 0;
#pragma unroll 1
  for (int step = 0; step < 32; ++step) {
    if (step < 31) {
      FO_LOADA((step + 1) * 32);       // issue loads early (T14)
      FO_STAGE_B(cur ^ 1, (step + 1) * 32);
    }

    unsigned short* L = lds + cur * 24576;
    bf16x8 a4[8], bH4[4], bL4[4];
#pragma unroll
    for (int m = 0; m < 8; ++m) {
      const int r = wm * 128 + m * 16 + l15;
      a4[m] = *reinterpret_cast<const bf16x8*>(L + r * 32 + (g ^ ((r >> 1) & 3)) * 8);
    }
#pragma unroll
    for (int n = 0; n < 4; ++n) {
      const int r = wn * 64 + n * 16 + l15;
      const int off = r * 32 + (g ^ ((r >> 1) & 3)) * 8;
      bH4[n] = *reinterpret_cast<const bf16x8*>(L + 8192 + off);
      bL4[n] = *reinterpret_cast<const bf16x8*>(L + 16384 + off);
    }
#pragma unroll
    for (int m = 0; m < 8; ++m)
#pragma unroll
      for (int n = 0; n < 4; ++n) {
        acc[m][n] = __builtin_amdgcn_mfma_f32_16x16x32_bf16(a4[m], bH4[n], acc[m][n], 0, 0, 0);
        acc[m][n] = __builtin_amdgcn_mfma_f32_16x16x32_bf16(a4[m], bL4[n], acc[m][n], 0, 0, 0);
      }

    if (step < 31) FO_WRITEA(cur ^ 1);  // idwt-compute + write late (T14)
    __syncthreads();
    cur ^= 1;
  }
#undef FO_LOADA
#undef FO_WRITEA
#undef FO_STAGE_B

  const int yrow0 = t0 + wm * 128;
#pragma unroll
  for (int n = 0; n < 4; ++n) {
    const int colg = o0 + wn * 64 + n * 16 + l15;
    const float bv = bias[colg];
#pragma unroll
    for (int m = 0; m < 8; ++m) {
      const int rbase = yrow0 + m * 16 + g * 4;
#pragma unroll
      for (int r = 0; r < 4; ++r)
        out[(size_t)(rbase + r) * 1024 + colg] = acc[m][n][r] + bv;
    }
  }
}

}  // namespace

extern "C" void kernel_launch(void* const* d_in, const int* in_sizes, int n_in,
                              void* d_out, int out_size, void* d_ws, size_t ws_size,
                              hipStream_t stream) {
  const float* x = (const float*)d_in[0];
  const float* w_approx = (const float*)d_in[1];
  const float* b_approx = (const float*)d_in[2];
  const float* w_detail = (const float*)d_in[3];
  const float* b_detail = (const float*)d_in[4];
  const float* w_out = (const float*)d_in[5];
  const float* b_out = (const float*)d_in[6];
  float* out = (float*)d_out;

  char* ws = (char*)d_ws;
  // merged A plane: 16 batches x 1026 rows x 1024 ushorts = 33,619,968 B
  unsigned short* A = (unsigned short*)(ws);
  unsigned short* pout = (unsigned short*)(ws + 33619968);   // 16x1024x1024 bf16 = 33,554,432 B
  unsigned short* wtAh = (unsigned short*)(ws + 134348800);  // 6,291,456 B each
  unsigned short* wtAl = (unsigned short*)(ws + 140640256);
  unsigned short* wtDh = (unsigned short*)(ws + 146931712);
  unsigned short* wtDl = (unsigned short*)(ws + 153223168);
  unsigned short* woH = (unsigned short*)(ws + 159514624);   // 2,097,152 B each
  unsigned short* woL = (unsigned short*)(ws + 161611776);

  fused_prep_kernel<<<7168, 256, 0, stream>>>(x, A, w_approx, w_detail,
                                              wtAh, wtAl, wtDh, wtDl,
                                              w_out, woH, woL);

  conv_mm_kernel<<<512, 512, 0, stream>>>(A, wtAh, wtAl, wtDh, wtDl,
                                          b_approx, b_detail, pout);

  fused_out_kernel<<<256, 512, 0, stream>>>(pout, woH, woL, b_out, out);
}